// Round 7
// baseline (255.876 us; speedup 1.0000x reference)
//
#include <hip/hip_runtime.h>
#include <hip/hip_bf16.h>
#include <math.h>

#define W_  160
#define H_  128
#define HW  20480
#define D_  48
#define C_  32
#define NV  4    // source views (views 1..4)
#define DB  8    // depth-block in k_warp

// conv/softmax tile
#define TX  16
#define TY  4
#define TXH 18
#define TYH 6
#define NCOL (TXH*TYH)   // 108

// ---------------- cross-lane helpers ----------------
template<int CTRL>
__device__ __forceinline__ float dpp_add(float s) {
  int t = __builtin_amdgcn_update_dpp(0, __float_as_int(s), CTRL, 0xF, 0xF, true);
  return s + __int_as_float(t);
}
__device__ __forceinline__ float swz_add4(float s) {
  int t = __builtin_amdgcn_ds_swizzle(__float_as_int(s), 0x101F);  // xor 4
  return s + __int_as_float(t);
}
template<int CTRL>
__device__ __forceinline__ float dpp_max(float s) {
  int t = __builtin_amdgcn_update_dpp(0, __float_as_int(s), CTRL, 0xF, 0xF, true);
  return fmaxf(s, __int_as_float(t));
}
__device__ __forceinline__ float swz_max4(float s) {
  int t = __builtin_amdgcn_ds_swizzle(__float_as_int(s), 0x101F);
  return fmaxf(s, __int_as_float(t));
}

// ---------------- tiny transform kernel ----------------

__device__ __forceinline__ void fuse_proj(const float* pm, float* P) {
  const float* E = pm;
  const float* K = pm + 16;
  for (int r = 0; r < 3; ++r)
    for (int c = 0; c < 4; ++c)
      P[r*4+c] = K[r*4+0]*E[0*4+c] + K[r*4+1]*E[1*4+c] + K[r*4+2]*E[2*4+c];
  for (int c = 0; c < 4; ++c) P[12+c] = E[12+c];
}

__device__ void invert4(const float* m, float* invOut) {
  float inv[16];
  inv[0]  =  m[5]*m[10]*m[15] - m[5]*m[11]*m[14] - m[9]*m[6]*m[15] + m[9]*m[7]*m[14] + m[13]*m[6]*m[11] - m[13]*m[7]*m[10];
  inv[4]  = -m[4]*m[10]*m[15] + m[4]*m[11]*m[14] + m[8]*m[6]*m[15] - m[8]*m[7]*m[14] - m[12]*m[6]*m[11] + m[12]*m[7]*m[10];
  inv[8]  =  m[4]*m[9]*m[15]  - m[4]*m[11]*m[13] - m[8]*m[5]*m[15] + m[8]*m[7]*m[13] + m[12]*m[5]*m[11] - m[12]*m[7]*m[9];
  inv[12] = -m[4]*m[9]*m[14]  + m[4]*m[10]*m[13] + m[8]*m[5]*m[14] - m[8]*m[6]*m[13] - m[12]*m[5]*m[10] + m[12]*m[6]*m[9];
  inv[1]  = -m[1]*m[10]*m[15] + m[1]*m[11]*m[14] + m[9]*m[2]*m[15] - m[9]*m[3]*m[14] - m[13]*m[2]*m[11] + m[13]*m[3]*m[10];
  inv[5]  =  m[0]*m[10]*m[15] - m[0]*m[11]*m[14] - m[8]*m[2]*m[15] + m[8]*m[3]*m[14] + m[12]*m[2]*m[11] - m[12]*m[3]*m[10];
  inv[9]  = -m[0]*m[9]*m[15]  + m[0]*m[11]*m[13] + m[8]*m[1]*m[15] - m[8]*m[3]*m[13] - m[12]*m[1]*m[11] + m[12]*m[3]*m[9];
  inv[13] =  m[0]*m[9]*m[14]  - m[0]*m[10]*m[13] - m[8]*m[1]*m[14] + m[8]*m[2]*m[13] + m[12]*m[1]*m[10] - m[12]*m[2]*m[9];
  inv[2]  =  m[1]*m[6]*m[15]  - m[1]*m[7]*m[14]  - m[5]*m[2]*m[15] + m[5]*m[3]*m[14] + m[13]*m[2]*m[7]  - m[13]*m[3]*m[6];
  inv[6]  = -m[0]*m[6]*m[15]  + m[0]*m[7]*m[14]  + m[4]*m[2]*m[15] - m[4]*m[3]*m[14] - m[12]*m[2]*m[7]  + m[12]*m[3]*m[6];
  inv[10] =  m[0]*m[5]*m[15]  - m[0]*m[7]*m[13]  - m[4]*m[1]*m[15] + m[4]*m[3]*m[13] + m[12]*m[1]*m[7]  - m[12]*m[3]*m[5];
  inv[14] = -m[0]*m[5]*m[14]  + m[0]*m[6]*m[13]  + m[4]*m[1]*m[14] - m[4]*m[2]*m[13] - m[12]*m[1]*m[6]  + m[12]*m[2]*m[5];
  inv[3]  = -m[1]*m[6]*m[11]  + m[1]*m[7]*m[10]  + m[5]*m[2]*m[11] - m[5]*m[3]*m[10] - m[9]*m[2]*m[7]   + m[9]*m[3]*m[6];
  inv[7]  =  m[0]*m[6]*m[11]  - m[0]*m[7]*m[10]  - m[4]*m[2]*m[11] + m[4]*m[3]*m[10] + m[8]*m[2]*m[7]   - m[8]*m[3]*m[6];
  inv[11] = -m[0]*m[5]*m[11]  + m[0]*m[7]*m[9]   + m[4]*m[1]*m[11] - m[4]*m[3]*m[9]  - m[8]*m[1]*m[7]   + m[8]*m[3]*m[5];
  inv[15] =  m[0]*m[5]*m[10]  - m[0]*m[6]*m[9]   - m[4]*m[1]*m[10] + m[4]*m[2]*m[9]  + m[8]*m[1]*m[6]   - m[8]*m[2]*m[5];
  float det = m[0]*inv[0] + m[1]*inv[4] + m[2]*inv[8] + m[3]*inv[12];
  det = 1.0f / det;
  for (int i = 0; i < 16; i++) invOut[i] = inv[i] * det;
}

// xf layout per src view v (0..3): [r00 r01 r02 r10 r11 r12 r20 r21 r22 t0 t1 t2]
__global__ void k_xform(const float* __restrict__ pm, float* __restrict__ xf) {
  if (blockIdx.x || threadIdx.x) return;
  float Pr[16], Pinv[16], Ps[16], M[16];
  fuse_proj(pm, Pr);
  invert4(Pr, Pinv);
  for (int v = 1; v <= NV; ++v) {
    fuse_proj(pm + v*32, Ps);
    for (int r = 0; r < 4; ++r)
      for (int c = 0; c < 4; ++c) {
        float a = 0.f;
        for (int k = 0; k < 4; ++k) a += Ps[r*4+k]*Pinv[k*4+c];
        M[r*4+c] = a;
      }
    float* o = xf + (v-1)*12;
    o[0]=M[0];  o[1]=M[1];  o[2]=M[2];
    o[3]=M[4];  o[4]=M[5];  o[5]=M[6];
    o[6]=M[8];  o[7]=M[9];  o[8]=M[10];
    o[9]=M[3];  o[10]=M[7]; o[11]=M[11];
  }
}

// ---------------- transpose (V,C,H,W) -> (V,HW,C), LDS-tiled ----------------
__global__ void __launch_bounds__(256)
k_transpose(const float* __restrict__ feat, float* __restrict__ tf) {
  __shared__ float tile[C_][64+1];
  int v  = blockIdx.y;
  int p0 = blockIdx.x * 64;
  int t  = threadIdx.x;

  int pl = t & 63;
  int cg = t >> 6;            // 0..3
  const float* src = feat + (size_t)v*C_*HW + p0 + pl;
  #pragma unroll
  for (int k = 0; k < 8; ++k) {
    int c = cg*8 + k;
    tile[c][pl] = src[(size_t)c*HW];
  }
  __syncthreads();

  int pp = t >> 2;            // pixel 0..63
  int co = (t & 3) * 8;       // channel offset
  float4 a, b;
  a.x = tile[co+0][pp]; a.y = tile[co+1][pp]; a.z = tile[co+2][pp]; a.w = tile[co+3][pp];
  b.x = tile[co+4][pp]; b.y = tile[co+5][pp]; b.z = tile[co+6][pp]; b.w = tile[co+7][pp];
  float* dst = tf + ((size_t)v*HW + p0 + pp)*C_ + co;
  *(float4*)dst = a;
  *(float4*)(dst+4) = b;
}

// ---------------- main warp + similarity + MLP + view-weight kernel --------
// Wave = 8 pixels x 8 slots. Per 8-depth block:
//   phase 1: each lane computes the descriptor for ONE (pixel, depth) item
//            with exact division, stages it to LDS (xor-swizzled).
//   phase 2: per depth, 2 LDS reads recover the descriptor; corner-reuse
//            skip when no lane's corner set moved (epipolar span ~1-4 px);
//            dot + xor-butterfly reduce leaves the full sim in ALL 8
//            channel-lanes; lane ch keeps the sim of depth (b*8+ch).
//   phase 3: one MLP eval per lane (64 lanes = the block's 64 (pixel,depth)
//            items), running per-lane logit max.
// Epilogue: xor max-reduce across ch-lanes, sigmoid, write vw.
__global__ void __launch_bounds__(256)
k_warp(const float* __restrict__ tf, const float* __restrict__ dv,
       const float* __restrict__ xf,
       const float* __restrict__ w0, const float* __restrict__ b0,
       const float* __restrict__ w1, const float* __restrict__ b1,
       const float* __restrict__ w2, const float* __restrict__ b2,
       float* __restrict__ sim_all, float* __restrict__ vw) {
  __shared__ int4   dso[4][64];
  __shared__ float2 dsf[4][64];

  int lane = threadIdx.x & 63;
  int wv = threadIdx.x >> 6;
  int ch = lane & 7;              // channel chunk (phase 2) / depth slot (phase 1/3)
  int pix = (lane >> 3) & 7;      // pixel within group
  int wvg = __builtin_amdgcn_readfirstlane((blockIdx.x*256 + threadIdx.x) >> 6);
  const int PGPV = HW/8;
  int pg = wvg % PGPV;
  int v  = wvg / PGPV;
  int p  = pg*8 + pix;

  float xpix = (float)(p % W_);
  float ypix = (float)(p / W_);

  const float* M = xf + v*12;
  float rx = M[0]*xpix + M[1]*ypix + M[2];
  float ry = M[3]*xpix + M[4]*ypix + M[5];
  float rz = M[6]*xpix + M[7]*ypix + M[8];
  float t0 = M[9], t1 = M[10], t2 = M[11];

  float4 rfc = *(const float4*)(tf + (size_t)p*C_ + ch*4);
  const char* tfb = (const char*)(tf + (size_t)(v+1)*HW*C_);
  const int chb = ch*16;
  const int ZB = (4-v)*HW*C_*4;   // byte offset (from view base) of zero pad

  float* simv = sim_all + (size_t)v*D_*HW + p;

  int4 P = make_int4(-1,-1,-1,-1);
  float d00 = 0.f, d01 = 0.f, d10 = 0.f, d11 = 0.f;
  float ymax = -3.0e38f;

  for (int b = 0; b < D_/DB; ++b) {
    // ---- phase 1: one descriptor per lane, staged to LDS ----
    int d1 = b*DB + ch;
    float dep = dv[(size_t)d1*HW + p];
    float Z  = rz*dep + t2;
    float px = (rx*dep + t0) / Z;       // exact IEEE divide (argmax safety)
    float py = (ry*dep + t1) / Z;
    float x0f = floorf(px), y0f = floorf(py);
    float wx1 = px - x0f;
    float wy1 = py - y0f;
    int x0 = (int)x0f, y0 = (int)y0f;
    int x1 = x0 + 1,   y1 = y0 + 1;
    bool vx0 = ((unsigned)x0 <= (unsigned)(W_-1));
    bool vx1 = ((unsigned)x1 <= (unsigned)(W_-1));
    bool vy0 = ((unsigned)y0 <= (unsigned)(H_-1));
    bool vy1 = ((unsigned)y1 <= (unsigned)(H_-1));
    int cx0 = min(max(x0, 0), W_-1);
    int cx1 = min(max(x1, 0), W_-1);
    int cy0 = min(max(y0, 0), H_-1);
    int cy1 = min(max(y1, 0), H_-1);
    int r0 = cy0*W_, r1 = cy1*W_;
    int o00 = (vx0 && vy0) ? (r0+cx0)*(C_*4) : ZB;
    int o01 = (vx1 && vy0) ? (r0+cx1)*(C_*4) : ZB;
    int o10 = (vx0 && vy1) ? (r1+cx0)*(C_*4) : ZB;
    int o11 = (vx1 && vy1) ? (r1+cx1)*(C_*4) : ZB;

    int key = (ch<<3) | (pix ^ ch);          // bank-uniform for write & read
    dso[wv][key] = make_int4(o00, o01, o10, o11);
    dsf[wv][key] = make_float2(wx1, wy1);

    // ---- phase 2: 8 depths; descriptor via 2 LDS reads ----
    float smy = 0.0f;   // this lane's sim (depth b*DB+ch)
    #pragma unroll
    for (int dd = 0; dd < DB; ++dd) {
      int it = (dd<<3) | (pix ^ dd);
      int4   O = dso[wv][it];
      float2 F = dsf[wv][it];
      float fx1 = F.x, fy1 = F.y;
      float fx0 = 1.0f - fx1, fy0 = 1.0f - fy1;
      float w00 = fx0*fy0, w01 = fx1*fy0, w10 = fx0*fy1, w11 = fx1*fy1;

      bool moved = (O.x != P.x) || (O.y != P.y) || (O.z != P.z) || (O.w != P.w);
      if (__any(moved)) {
        float4 a  = *(const float4*)(tfb + (O.x + chb));
        float4 bq = *(const float4*)(tfb + (O.y + chb));
        float4 g  = *(const float4*)(tfb + (O.z + chb));
        float4 e  = *(const float4*)(tfb + (O.w + chb));
        d00 = a.x*rfc.x  + a.y*rfc.y  + a.z*rfc.z  + a.w*rfc.w;
        d01 = bq.x*rfc.x + bq.y*rfc.y + bq.z*rfc.z + bq.w*rfc.w;
        d10 = g.x*rfc.x  + g.y*rfc.y  + g.z*rfc.z  + g.w*rfc.w;
        d11 = e.x*rfc.x  + e.y*rfc.y  + e.z*rfc.z  + e.w*rfc.w;
      }
      P = O;

      float s = w00*d00 + w01*d01 + w10*d10 + w11*d11;
      s = dpp_add<0xB1>(s);   // xor 1
      s = dpp_add<0x4E>(s);   // xor 2
      s = swz_add4(s);        // xor 4 -> full sum in ALL 8 ch lanes
      float sfin = s * (1.0f/(float)C_);

      if (ch == dd) smy = sfin;                       // keep my slot's sim
      if (ch == 0) simv[(size_t)(b*DB + dd)*HW] = sfin;
    }

    // ---- phase 3: one MLP eval per lane (this block's 64 items) ----
    {
      float acc0 = b1[0], acc1 = b1[1], acc2 = b1[2], acc3 = b1[3];
      float acc4 = b1[4], acc5 = b1[5], acc6 = b1[6], acc7 = b1[7];
      #pragma unroll
      for (int o = 0; o < 16; ++o) {
        float h = fmaxf(fmaf(w0[o], smy, b0[o]), 0.0f);
        acc0 = fmaf(w1[0*16+o], h, acc0);
        acc1 = fmaf(w1[1*16+o], h, acc1);
        acc2 = fmaf(w1[2*16+o], h, acc2);
        acc3 = fmaf(w1[3*16+o], h, acc3);
        acc4 = fmaf(w1[4*16+o], h, acc4);
        acc5 = fmaf(w1[5*16+o], h, acc5);
        acc6 = fmaf(w1[6*16+o], h, acc6);
        acc7 = fmaf(w1[7*16+o], h, acc7);
      }
      float yv = b2[0];
      yv = fmaf(w2[0], fmaxf(acc0, 0.0f), yv);
      yv = fmaf(w2[1], fmaxf(acc1, 0.0f), yv);
      yv = fmaf(w2[2], fmaxf(acc2, 0.0f), yv);
      yv = fmaf(w2[3], fmaxf(acc3, 0.0f), yv);
      yv = fmaf(w2[4], fmaxf(acc4, 0.0f), yv);
      yv = fmaf(w2[5], fmaxf(acc5, 0.0f), yv);
      yv = fmaf(w2[6], fmaxf(acc6, 0.0f), yv);
      yv = fmaf(w2[7], fmaxf(acc7, 0.0f), yv);
      ymax = fmaxf(ymax, yv);
    }
  }

  // ---- epilogue: max over the 8 ch-lanes (covers all 48 depths), sigmoid ----
  float m = ymax;
  m = dpp_max<0xB1>(m);
  m = dpp_max<0x4E>(m);
  m = swz_max4(m);
  if (ch == 0) vw[(size_t)v*HW + p] = 1.0f / (1.0f + expf(-m));
}

// ---------------- fused: fuse + 3x3x3 conv + softmax/argmax ----------------
__global__ void __launch_bounds__(256)
k_fct(const float* __restrict__ sim_all, const float* __restrict__ vw,
      const float* __restrict__ rw, const float* __restrict__ rb,
      const float* __restrict__ dv, float* __restrict__ out) {
  __shared__ float sfus[D_][TYH][TXH+1];
  __shared__ float scost[D_][64];
  __shared__ float svw[NV][NCOL];
  __shared__ float sinvw[NCOL];
  __shared__ int   sgpc[NCOL];

  int tid = threadIdx.x;
  int gx0 = blockIdx.x*TX;
  int gy0 = blockIdx.y*TY;

  // phase A: per-column view weights / inverse wsum / clamped pixel index
  if (tid < NCOL) {
    int yy = tid / TXH, xx = tid % TXH;
    int gy = gy0 + yy - 1, gx = gx0 + xx - 1;
    bool valid = (gx >= 0) && (gx < W_) && (gy >= 0) && (gy < H_);
    int gp = min(max(gy,0),H_-1)*W_ + min(max(gx,0),W_-1);
    sgpc[tid] = gp;
    float a0 = vw[0*HW+gp], a1 = vw[1*HW+gp], a2 = vw[2*HW+gp], a3 = vw[3*HW+gp];
    float inv = valid ? 1.0f/(1e-5f + a0+a1+a2+a3) : 0.0f;
    if (!valid) { a0=a1=a2=a3=0.f; }
    svw[0][tid]=a0; svw[1][tid]=a1; svw[2][tid]=a2; svw[3][tid]=a3;
    sinvw[tid] = inv;
  }
  __syncthreads();

  // phase B: fill fused volume tile (invalid columns auto-zero via weights)
  for (int j = tid; j < D_*NCOL; j += 256) {
    int d = j / NCOL, r = j % NCOL;
    int gp = sgpc[r];
    float s0 = sim_all[(size_t)(0*D_+d)*HW + gp];
    float s1 = sim_all[(size_t)(1*D_+d)*HW + gp];
    float s2 = sim_all[(size_t)(2*D_+d)*HW + gp];
    float s3 = sim_all[(size_t)(3*D_+d)*HW + gp];
    float val = (s0*svw[0][r] + s1*svw[1][r] + s2*svw[2][r] + s3*svw[3][r]) * sinvw[r];
    int yy = r / TXH, xx = r % TXH;
    sfus[d][yy][xx] = val;
  }
  __syncthreads();

  // phase C: 3x3x3 conv; thread = (pixel, depth-group of 12)
  {
    int pid = tid & 63;
    int dg  = tid >> 6;
    int px = pid & 15, py = pid >> 4;
    float kw[27];
    #pragma unroll
    for (int i = 0; i < 27; ++i) kw[i] = rw[i];
    float bias = rb[0];

    float pm1[9], p0[9], pp1[9];
    int d0 = dg*12;
    #pragma unroll
    for (int i = 0; i < 9; ++i) {
      int ky = i/3, kx = i%3;
      pm1[i] = (d0 > 0) ? sfus[d0-1][py+ky][px+kx] : 0.0f;
      p0[i]  = sfus[d0][py+ky][px+kx];
    }
    #pragma unroll
    for (int k = 0; k < 12; ++k) {
      int d = d0 + k;
      #pragma unroll
      for (int i = 0; i < 9; ++i) {
        int ky = i/3, kx = i%3;
        pp1[i] = (d+1 < D_) ? sfus[d+1][py+ky][px+kx] : 0.0f;
      }
      float acc = bias;
      #pragma unroll
      for (int i = 0; i < 9; ++i) acc += pm1[i]*kw[i];
      #pragma unroll
      for (int i = 0; i < 9; ++i) acc += p0[i]*kw[9+i];
      #pragma unroll
      for (int i = 0; i < 9; ++i) acc += pp1[i]*kw[18+i];
      scost[d][pid] = acc;
      #pragma unroll
      for (int i = 0; i < 9; ++i) { pm1[i] = p0[i]; p0[i] = pp1[i]; }
    }
  }
  __syncthreads();

  // phase D: softmax / argmax / outputs, one thread per pixel
  if (tid < 64) {
    int tx = tid & 15, ty = tid >> 4;
    int gx = gx0 + tx, gy = gy0 + ty;
    int gp = gy*W_ + gx;
    float vmax = scost[0][tid];
    int am = 0;
    #pragma unroll
    for (int d = 1; d < D_; ++d) {
      float c = scost[d][tid];
      if (c > vmax) { vmax = c; am = d; }
    }
    float sum = 0.0f;
    #pragma unroll
    for (int d = 0; d < D_; ++d) sum += expf(scost[d][tid] - vmax);
    float inv = 1.0f / sum;
    #pragma unroll
    for (int d = 0; d < D_; ++d)
      out[(size_t)(2*HW) + (size_t)d*HW + gp] = expf(scost[d][tid] - vmax) * inv;
    out[gp] = dv[(size_t)am*HW + gp];
    out[HW + gp] = inv;
    // view_weights output
    int rint = (ty+1)*TXH + (tx+1);
    #pragma unroll
    for (int v = 0; v < NV; ++v)
      out[(size_t)(2*HW + D_*HW) + (size_t)v*HW + gp] = svw[v][rint];
  }
}

// ---------------- launch ----------------
extern "C" void kernel_launch(void* const* d_in, const int* in_sizes, int n_in,
                              void* d_out, int out_size, void* d_ws, size_t ws_size,
                              hipStream_t stream) {
  const float* feat = (const float*)d_in[0];
  const float* pm   = (const float*)d_in[1];
  const float* dv   = (const float*)d_in[2];
  const float* w0   = (const float*)d_in[3];
  const float* b0   = (const float*)d_in[4];
  const float* w1   = (const float*)d_in[5];
  const float* b1   = (const float*)d_in[6];
  const float* w2   = (const float*)d_in[7];
  const float* b2   = (const float*)d_in[8];
  const float* rw   = (const float*)d_in[9];
  const float* rb   = (const float*)d_in[10];
  float* out = (float*)d_out;
  float* ws  = (float*)d_ws;

  // workspace layout (floats)
  float* xf   = ws;                  // 48 (pad 64)
  float* tf   = ws + 64;             // 5*HW*C + 64 zero-pad = 3,276,864 floats
  float* sim  = ws + 3276928;        // 4*48*HW = 3,932,160
  float* vw   = ws + 7209088;        // 4*HW = 81,920
  // high-water mark: ~7.29M floats = ~27.8 MB

  hipLaunchKernelGGL(k_xform, dim3(1), dim3(64), 0, stream, pm, xf);
  hipMemsetAsync(tf + (size_t)5*HW*C_, 0, 64*sizeof(float), stream);
  hipLaunchKernelGGL(k_transpose, dim3(HW/64, 5), dim3(256), 0, stream, feat, tf);
  hipLaunchKernelGGL(k_warp, dim3((NV*HW*8)/256), dim3(256), 0, stream,
                     tf, dv, xf, w0, b0, w1, b1, w2, b2, sim, vw);
  hipLaunchKernelGGL(k_fct, dim3(W_/TX, H_/TY), dim3(256), 0, stream,
                     sim, vw, rw, rb, dv, out);
}

// Round 8
// 105.200 us; speedup vs baseline: 2.4323x; 2.4323x over previous
//
#include <hip/hip_runtime.h>
#include <hip/hip_bf16.h>
#include <math.h>

#define W_  160
#define H_  128
#define HW  20480
#define D_  48
#define C_  32
#define NV  4    // source views (views 1..4)
#define DB  8    // depth-block in k_warp

// conv/softmax tile
#define TX  16
#define TY  4
#define TXH 18
#define TYH 6
#define NCOL (TXH*TYH)   // 108

// ---------------- cross-lane helpers ----------------
template<int CTRL>
__device__ __forceinline__ float dpp_add(float s) {
  int t = __builtin_amdgcn_update_dpp(0, __float_as_int(s), CTRL, 0xF, 0xF, true);
  return s + __int_as_float(t);
}
__device__ __forceinline__ float swz_add4(float s) {
  int t = __builtin_amdgcn_ds_swizzle(__float_as_int(s), 0x101F);  // xor 4
  return s + __int_as_float(t);
}

// monotone float<->uint ordering (for atomic max)
__device__ __forceinline__ unsigned ordf(float f) {
  unsigned b = __float_as_uint(f);
  return b ^ (((int)b >> 31) | 0x80000000u);
}
__device__ __forceinline__ float deordf(unsigned u) {
  unsigned b = (u & 0x80000000u) ? (u ^ 0x80000000u) : ~u;
  return __uint_as_float(b);
}

// ---------------- tiny transform kernel ----------------

__device__ __forceinline__ void fuse_proj(const float* pm, float* P) {
  const float* E = pm;
  const float* K = pm + 16;
  for (int r = 0; r < 3; ++r)
    for (int c = 0; c < 4; ++c)
      P[r*4+c] = K[r*4+0]*E[0*4+c] + K[r*4+1]*E[1*4+c] + K[r*4+2]*E[2*4+c];
  for (int c = 0; c < 4; ++c) P[12+c] = E[12+c];
}

__device__ void invert4(const float* m, float* invOut) {
  float inv[16];
  inv[0]  =  m[5]*m[10]*m[15] - m[5]*m[11]*m[14] - m[9]*m[6]*m[15] + m[9]*m[7]*m[14] + m[13]*m[6]*m[11] - m[13]*m[7]*m[10];
  inv[4]  = -m[4]*m[10]*m[15] + m[4]*m[11]*m[14] + m[8]*m[6]*m[15] - m[8]*m[7]*m[14] - m[12]*m[6]*m[11] + m[12]*m[7]*m[10];
  inv[8]  =  m[4]*m[9]*m[15]  - m[4]*m[11]*m[13] - m[8]*m[5]*m[15] + m[8]*m[7]*m[13] + m[12]*m[5]*m[11] - m[12]*m[7]*m[9];
  inv[12] = -m[4]*m[9]*m[14]  + m[4]*m[10]*m[13] + m[8]*m[5]*m[14] - m[8]*m[6]*m[13] - m[12]*m[5]*m[10] + m[12]*m[6]*m[9];
  inv[1]  = -m[1]*m[10]*m[15] + m[1]*m[11]*m[14] + m[9]*m[2]*m[15] - m[9]*m[3]*m[14] - m[13]*m[2]*m[11] + m[13]*m[3]*m[10];
  inv[5]  =  m[0]*m[10]*m[15] - m[0]*m[11]*m[14] - m[8]*m[2]*m[15] + m[8]*m[3]*m[14] + m[12]*m[2]*m[11] - m[12]*m[3]*m[10];
  inv[9]  = -m[0]*m[9]*m[15]  + m[0]*m[11]*m[13] + m[8]*m[1]*m[15] - m[8]*m[3]*m[13] - m[12]*m[1]*m[11] + m[12]*m[3]*m[9];
  inv[13] =  m[0]*m[9]*m[14]  - m[0]*m[10]*m[13] - m[8]*m[1]*m[14] + m[8]*m[2]*m[13] + m[12]*m[1]*m[10] - m[12]*m[2]*m[9];
  inv[2]  =  m[1]*m[6]*m[15]  - m[1]*m[7]*m[14]  - m[5]*m[2]*m[15] + m[5]*m[3]*m[14] + m[13]*m[2]*m[7]  - m[13]*m[3]*m[6];
  inv[6]  = -m[0]*m[6]*m[15]  + m[0]*m[7]*m[14]  + m[4]*m[2]*m[15] - m[4]*m[3]*m[14] - m[12]*m[2]*m[7]  + m[12]*m[3]*m[6];
  inv[10] =  m[0]*m[5]*m[15]  - m[0]*m[7]*m[13]  - m[4]*m[1]*m[15] + m[4]*m[3]*m[13] + m[12]*m[1]*m[7]  - m[12]*m[3]*m[5];
  inv[14] = -m[0]*m[5]*m[14]  + m[0]*m[6]*m[13]  + m[4]*m[1]*m[14] - m[4]*m[2]*m[13] - m[12]*m[1]*m[6]  + m[12]*m[2]*m[5];
  inv[3]  = -m[1]*m[6]*m[11]  + m[1]*m[7]*m[10]  + m[5]*m[2]*m[11] - m[5]*m[3]*m[10] - m[9]*m[2]*m[7]   + m[9]*m[3]*m[6];
  inv[7]  =  m[0]*m[6]*m[11]  - m[0]*m[7]*m[10]  - m[4]*m[2]*m[11] + m[4]*m[3]*m[10] + m[8]*m[2]*m[7]   - m[8]*m[3]*m[6];
  inv[11] = -m[0]*m[5]*m[11]  + m[0]*m[7]*m[9]   + m[4]*m[1]*m[11] - m[4]*m[3]*m[9]  - m[8]*m[1]*m[7]   + m[8]*m[3]*m[5];
  inv[15] =  m[0]*m[5]*m[10]  - m[0]*m[6]*m[9]   - m[4]*m[1]*m[10] + m[4]*m[2]*m[9]  + m[8]*m[1]*m[6]   - m[8]*m[2]*m[5];
  float det = m[0]*inv[0] + m[1]*inv[4] + m[2]*inv[8] + m[3]*inv[12];
  det = 1.0f / det;
  for (int i = 0; i < 16; i++) invOut[i] = inv[i] * det;
}

// xf layout per src view v (0..3): [r00 r01 r02 r10 r11 r12 r20 r21 r22 t0 t1 t2]
__global__ void k_xform(const float* __restrict__ pm, float* __restrict__ xf) {
  if (blockIdx.x || threadIdx.x) return;
  float Pr[16], Pinv[16], Ps[16], M[16];
  fuse_proj(pm, Pr);
  invert4(Pr, Pinv);
  for (int v = 1; v <= NV; ++v) {
    fuse_proj(pm + v*32, Ps);
    for (int r = 0; r < 4; ++r)
      for (int c = 0; c < 4; ++c) {
        float a = 0.f;
        for (int k = 0; k < 4; ++k) a += Ps[r*4+k]*Pinv[k*4+c];
        M[r*4+c] = a;
      }
    float* o = xf + (v-1)*12;
    o[0]=M[0];  o[1]=M[1];  o[2]=M[2];
    o[3]=M[4];  o[4]=M[5];  o[5]=M[6];
    o[6]=M[8];  o[7]=M[9];  o[8]=M[10];
    o[9]=M[3];  o[10]=M[7]; o[11]=M[11];
  }
}

// ---------------- transpose (V,C,H,W) -> (V,HW,C), LDS-tiled ----------------
__global__ void __launch_bounds__(256)
k_transpose(const float* __restrict__ feat, float* __restrict__ tf) {
  __shared__ float tile[C_][64+1];
  int v  = blockIdx.y;
  int p0 = blockIdx.x * 64;
  int t  = threadIdx.x;

  int pl = t & 63;
  int cg = t >> 6;            // 0..3
  const float* src = feat + (size_t)v*C_*HW + p0 + pl;
  #pragma unroll
  for (int k = 0; k < 8; ++k) {
    int c = cg*8 + k;
    tile[c][pl] = src[(size_t)c*HW];
  }
  __syncthreads();

  int pp = t >> 2;            // pixel 0..63
  int co = (t & 3) * 8;       // channel offset
  float4 a, b;
  a.x = tile[co+0][pp]; a.y = tile[co+1][pp]; a.z = tile[co+2][pp]; a.w = tile[co+3][pp];
  b.x = tile[co+4][pp]; b.y = tile[co+5][pp]; b.z = tile[co+6][pp]; b.w = tile[co+7][pp];
  float* dst = tf + ((size_t)v*HW + p0 + pp)*C_ + co;
  *(float4*)dst = a;
  *(float4*)(dst+4) = b;
}

// ---------------- main warp + similarity kernel (R6 structure) ----------------
__global__ void __launch_bounds__(256)
k_warp(const float* __restrict__ tf, const float* __restrict__ dv,
       const float* __restrict__ xf, float* __restrict__ sim_all) {
  __shared__ int4   dso[4][64];
  __shared__ float2 dsf[4][64];

  int lane = threadIdx.x & 63;
  int wv = threadIdx.x >> 6;
  int ch = lane & 7;              // channel chunk (phase 2) / depth slot (phase 1)
  int pix = (lane >> 3) & 7;      // pixel within group
  int wvg = __builtin_amdgcn_readfirstlane((blockIdx.x*256 + threadIdx.x) >> 6);
  const int PGPV = HW/8;
  int pg = wvg % PGPV;
  int v  = wvg / PGPV;
  int p  = pg*8 + pix;

  float xpix = (float)(p % W_);
  float ypix = (float)(p / W_);

  const float* M = xf + v*12;
  float rx = M[0]*xpix + M[1]*ypix + M[2];
  float ry = M[3]*xpix + M[4]*ypix + M[5];
  float rz = M[6]*xpix + M[7]*ypix + M[8];
  float t0 = M[9], t1 = M[10], t2 = M[11];

  float4 rfc = *(const float4*)(tf + (size_t)p*C_ + ch*4);
  const char* tfb = (const char*)(tf + (size_t)(v+1)*HW*C_);
  const int chb = ch*16;
  const int ZB = (4-v)*HW*C_*4;   // byte offset (from view base) of zero pad

  float* simv = sim_all + (size_t)v*D_*HW + p;

  int4 P = make_int4(-1,-1,-1,-1);
  float d00 = 0.f, d01 = 0.f, d10 = 0.f, d11 = 0.f;

  for (int b = 0; b < D_/DB; ++b) {
    // ---- phase 1: one descriptor per lane, staged to LDS ----
    int d1 = b*DB + ch;
    float dep = dv[(size_t)d1*HW + p];
    float Z  = rz*dep + t2;
    float px = (rx*dep + t0) / Z;       // exact IEEE divide (argmax safety)
    float py = (ry*dep + t1) / Z;
    float x0f = floorf(px), y0f = floorf(py);
    float wx1 = px - x0f;
    float wy1 = py - y0f;
    int x0 = (int)x0f, y0 = (int)y0f;
    int x1 = x0 + 1,   y1 = y0 + 1;
    bool vx0 = ((unsigned)x0 <= (unsigned)(W_-1));
    bool vx1 = ((unsigned)x1 <= (unsigned)(W_-1));
    bool vy0 = ((unsigned)y0 <= (unsigned)(H_-1));
    bool vy1 = ((unsigned)y1 <= (unsigned)(H_-1));
    int cx0 = min(max(x0, 0), W_-1);
    int cx1 = min(max(x1, 0), W_-1);
    int cy0 = min(max(y0, 0), H_-1);
    int cy1 = min(max(y1, 0), H_-1);
    int r0 = cy0*W_, r1 = cy1*W_;
    int o00 = (vx0 && vy0) ? (r0+cx0)*(C_*4) : ZB;
    int o01 = (vx1 && vy0) ? (r0+cx1)*(C_*4) : ZB;
    int o10 = (vx0 && vy1) ? (r1+cx0)*(C_*4) : ZB;
    int o11 = (vx1 && vy1) ? (r1+cx1)*(C_*4) : ZB;

    int key = (ch<<3) | (pix ^ ch);          // bank-uniform for write & read
    dso[wv][key] = make_int4(o00, o01, o10, o11);
    dsf[wv][key] = make_float2(wx1, wy1);

    // ---- phase 2: 8 depths; descriptor via 2 LDS reads ----
    #pragma unroll
    for (int dd = 0; dd < DB; ++dd) {
      int it = (dd<<3) | (pix ^ dd);
      int4   O = dso[wv][it];
      float2 F = dsf[wv][it];
      float fx1 = F.x, fy1 = F.y;
      float fx0 = 1.0f - fx1, fy0 = 1.0f - fy1;
      float w00 = fx0*fy0, w01 = fx1*fy0, w10 = fx0*fy1, w11 = fx1*fy1;

      bool moved = (O.x != P.x) || (O.y != P.y) || (O.z != P.z) || (O.w != P.w);
      if (__any(moved)) {
        float4 a  = *(const float4*)(tfb + (O.x + chb));
        float4 bq = *(const float4*)(tfb + (O.y + chb));
        float4 g  = *(const float4*)(tfb + (O.z + chb));
        float4 e  = *(const float4*)(tfb + (O.w + chb));
        d00 = a.x*rfc.x  + a.y*rfc.y  + a.z*rfc.z  + a.w*rfc.w;
        d01 = bq.x*rfc.x + bq.y*rfc.y + bq.z*rfc.z + bq.w*rfc.w;
        d10 = g.x*rfc.x  + g.y*rfc.y  + g.z*rfc.z  + g.w*rfc.w;
        d11 = e.x*rfc.x  + e.y*rfc.y  + e.z*rfc.z  + e.w*rfc.w;
      }
      P = O;

      float s = w00*d00 + w01*d01 + w10*d10 + w11*d11;
      s = dpp_add<0xB1>(s);   // xor 1
      s = dpp_add<0x4E>(s);   // xor 2
      s = swz_add4(s);        // xor 4
      if (ch == 0) simv[(size_t)(b*DB + dd)*HW] = s * (1.0f/(float)C_);
    }
  }
}

// ---------------- MLP: one eval per thread, atomic-max logit -------------
// idx = (v,d,p) with p fastest == flat index into sim_all. Straight-line body
// so the 177 weight scalar-loads are issued once per wave in wide batches.
__global__ void __launch_bounds__(256)
k_mlp(const float* __restrict__ sim_all,
      const float* __restrict__ w0, const float* __restrict__ b0,
      const float* __restrict__ w1, const float* __restrict__ b1,
      const float* __restrict__ w2, const float* __restrict__ b2,
      unsigned* __restrict__ vwu) {
  int idx = blockIdx.x*blockDim.x + threadIdx.x;
  if (idx >= NV*D_*HW) return;
  int p = idx % HW;
  int v = idx / (D_*HW);

  float s = sim_all[idx];

  float acc0 = b1[0], acc1 = b1[1], acc2 = b1[2], acc3 = b1[3];
  float acc4 = b1[4], acc5 = b1[5], acc6 = b1[6], acc7 = b1[7];
  #pragma unroll
  for (int o = 0; o < 16; ++o) {
    float h = fmaxf(fmaf(w0[o], s, b0[o]), 0.0f);
    acc0 = fmaf(w1[0*16+o], h, acc0);
    acc1 = fmaf(w1[1*16+o], h, acc1);
    acc2 = fmaf(w1[2*16+o], h, acc2);
    acc3 = fmaf(w1[3*16+o], h, acc3);
    acc4 = fmaf(w1[4*16+o], h, acc4);
    acc5 = fmaf(w1[5*16+o], h, acc5);
    acc6 = fmaf(w1[6*16+o], h, acc6);
    acc7 = fmaf(w1[7*16+o], h, acc7);
  }
  float yv = b2[0];
  yv = fmaf(w2[0], fmaxf(acc0, 0.0f), yv);
  yv = fmaf(w2[1], fmaxf(acc1, 0.0f), yv);
  yv = fmaf(w2[2], fmaxf(acc2, 0.0f), yv);
  yv = fmaf(w2[3], fmaxf(acc3, 0.0f), yv);
  yv = fmaf(w2[4], fmaxf(acc4, 0.0f), yv);
  yv = fmaf(w2[5], fmaxf(acc5, 0.0f), yv);
  yv = fmaf(w2[6], fmaxf(acc6, 0.0f), yv);
  yv = fmaf(w2[7], fmaxf(acc7, 0.0f), yv);

  atomicMax(&vwu[(size_t)v*HW + p], ordf(yv));
}

// ---------------- decode + sigmoid -> view weights ----------------
__global__ void k_vw(const unsigned* __restrict__ vwu, float* __restrict__ vw) {
  int idx = blockIdx.x*blockDim.x + threadIdx.x;
  if (idx >= NV*HW) return;
  float m = deordf(vwu[idx]);
  vw[idx] = 1.0f / (1.0f + expf(-m));
}

// ---------------- fused: fuse + 3x3x3 conv + softmax/argmax ----------------
__global__ void __launch_bounds__(256)
k_fct(const float* __restrict__ sim_all, const float* __restrict__ vw,
      const float* __restrict__ rw, const float* __restrict__ rb,
      const float* __restrict__ dv, float* __restrict__ out) {
  __shared__ float sfus[D_][TYH][TXH+1];
  __shared__ float scost[D_][64];
  __shared__ float svw[NV][NCOL];
  __shared__ float sinvw[NCOL];
  __shared__ int   sgpc[NCOL];

  int tid = threadIdx.x;
  int gx0 = blockIdx.x*TX;
  int gy0 = blockIdx.y*TY;

  // phase A: per-column view weights / inverse wsum / clamped pixel index
  if (tid < NCOL) {
    int yy = tid / TXH, xx = tid % TXH;
    int gy = gy0 + yy - 1, gx = gx0 + xx - 1;
    bool valid = (gx >= 0) && (gx < W_) && (gy >= 0) && (gy < H_);
    int gp = min(max(gy,0),H_-1)*W_ + min(max(gx,0),W_-1);
    sgpc[tid] = gp;
    float a0 = vw[0*HW+gp], a1 = vw[1*HW+gp], a2 = vw[2*HW+gp], a3 = vw[3*HW+gp];
    float inv = valid ? 1.0f/(1e-5f + a0+a1+a2+a3) : 0.0f;
    if (!valid) { a0=a1=a2=a3=0.f; }
    svw[0][tid]=a0; svw[1][tid]=a1; svw[2][tid]=a2; svw[3][tid]=a3;
    sinvw[tid] = inv;
  }
  __syncthreads();

  // phase B: fill fused volume tile (invalid columns auto-zero via weights)
  for (int j = tid; j < D_*NCOL; j += 256) {
    int d = j / NCOL, r = j % NCOL;
    int gp = sgpc[r];
    float s0 = sim_all[(size_t)(0*D_+d)*HW + gp];
    float s1 = sim_all[(size_t)(1*D_+d)*HW + gp];
    float s2 = sim_all[(size_t)(2*D_+d)*HW + gp];
    float s3 = sim_all[(size_t)(3*D_+d)*HW + gp];
    float val = (s0*svw[0][r] + s1*svw[1][r] + s2*svw[2][r] + s3*svw[3][r]) * sinvw[r];
    int yy = r / TXH, xx = r % TXH;
    sfus[d][yy][xx] = val;
  }
  __syncthreads();

  // phase C: 3x3x3 conv; thread = (pixel, depth-group of 12)
  {
    int pid = tid & 63;
    int dg  = tid >> 6;
    int px = pid & 15, py = pid >> 4;
    float kw[27];
    #pragma unroll
    for (int i = 0; i < 27; ++i) kw[i] = rw[i];
    float bias = rb[0];

    float pm1[9], p0[9], pp1[9];
    int d0 = dg*12;
    #pragma unroll
    for (int i = 0; i < 9; ++i) {
      int ky = i/3, kx = i%3;
      pm1[i] = (d0 > 0) ? sfus[d0-1][py+ky][px+kx] : 0.0f;
      p0[i]  = sfus[d0][py+ky][px+kx];
    }
    #pragma unroll
    for (int k = 0; k < 12; ++k) {
      int d = d0 + k;
      #pragma unroll
      for (int i = 0; i < 9; ++i) {
        int ky = i/3, kx = i%3;
        pp1[i] = (d+1 < D_) ? sfus[d+1][py+ky][px+kx] : 0.0f;
      }
      float acc = bias;
      #pragma unroll
      for (int i = 0; i < 9; ++i) acc += pm1[i]*kw[i];
      #pragma unroll
      for (int i = 0; i < 9; ++i) acc += p0[i]*kw[9+i];
      #pragma unroll
      for (int i = 0; i < 9; ++i) acc += pp1[i]*kw[18+i];
      scost[d][pid] = acc;
      #pragma unroll
      for (int i = 0; i < 9; ++i) { pm1[i] = p0[i]; p0[i] = pp1[i]; }
    }
  }
  __syncthreads();

  // phase D: softmax / argmax / outputs, one thread per pixel
  if (tid < 64) {
    int tx = tid & 15, ty = tid >> 4;
    int gx = gx0 + tx, gy = gy0 + ty;
    int gp = gy*W_ + gx;
    float vmax = scost[0][tid];
    int am = 0;
    #pragma unroll
    for (int d = 1; d < D_; ++d) {
      float c = scost[d][tid];
      if (c > vmax) { vmax = c; am = d; }
    }
    float sum = 0.0f;
    #pragma unroll
    for (int d = 0; d < D_; ++d) sum += expf(scost[d][tid] - vmax);
    float inv = 1.0f / sum;
    #pragma unroll
    for (int d = 0; d < D_; ++d)
      out[(size_t)(2*HW) + (size_t)d*HW + gp] = expf(scost[d][tid] - vmax) * inv;
    out[gp] = dv[(size_t)am*HW + gp];
    out[HW + gp] = inv;
    // view_weights output
    int rint = (ty+1)*TXH + (tx+1);
    #pragma unroll
    for (int v = 0; v < NV; ++v)
      out[(size_t)(2*HW + D_*HW) + (size_t)v*HW + gp] = svw[v][rint];
  }
}

// ---------------- launch ----------------
extern "C" void kernel_launch(void* const* d_in, const int* in_sizes, int n_in,
                              void* d_out, int out_size, void* d_ws, size_t ws_size,
                              hipStream_t stream) {
  const float* feat = (const float*)d_in[0];
  const float* pm   = (const float*)d_in[1];
  const float* dv   = (const float*)d_in[2];
  const float* w0   = (const float*)d_in[3];
  const float* b0   = (const float*)d_in[4];
  const float* w1   = (const float*)d_in[5];
  const float* b1   = (const float*)d_in[6];
  const float* w2   = (const float*)d_in[7];
  const float* b2   = (const float*)d_in[8];
  const float* rw   = (const float*)d_in[9];
  const float* rb   = (const float*)d_in[10];
  float* out = (float*)d_out;
  float* ws  = (float*)d_ws;

  // workspace layout (floats)
  float*    xf  = ws;                        // 48 (pad 64)
  float*    tf  = ws + 64;                   // 5*HW*C + 64 zero-pad
  float*    sim = ws + 3276928;              // 4*48*HW = 3,932,160
  unsigned* vwu = (unsigned*)(ws + 7209088); // 4*HW = 81,920
  float*    vw  = ws + 7291008;              // 4*HW = 81,920
  // high-water mark: ~7.37M floats = ~29.5 MB

  hipLaunchKernelGGL(k_xform, dim3(1), dim3(64), 0, stream, pm, xf);
  hipMemsetAsync(tf + (size_t)5*HW*C_, 0, 64*sizeof(float), stream);
  hipMemsetAsync(vwu, 0, (size_t)NV*HW*sizeof(unsigned), stream);
  hipLaunchKernelGGL(k_transpose, dim3(HW/64, 5), dim3(256), 0, stream, feat, tf);
  hipLaunchKernelGGL(k_warp, dim3((NV*HW*8)/256), dim3(256), 0, stream, tf, dv, xf, sim);
  hipLaunchKernelGGL(k_mlp, dim3((NV*D_*HW)/256), dim3(256), 0, stream,
                     sim, w0, b0, w1, b1, w2, b2, vwu);
  hipLaunchKernelGGL(k_vw, dim3((NV*HW)/256), dim3(256), 0, stream, vwu, vw);
  hipLaunchKernelGGL(k_fct, dim3(W_/TX, H_/TY), dim3(256), 0, stream,
                     sim, vw, rw, rb, dv, out);
}

// Round 9
// 93.863 us; speedup vs baseline: 2.7260x; 1.1208x over previous
//
#include <hip/hip_runtime.h>
#include <hip/hip_bf16.h>
#include <math.h>

#define W_  160
#define H_  128
#define HW  20480
#define D_  48
#define C_  32
#define NV  4    // source views (views 1..4)
#define DB  8    // depth-block in k_warp

// conv/softmax tile
#define TX  16
#define TY  4
#define TXH 18
#define TYH 6
#define NCOL (TXH*TYH)   // 108

// ---------------- cross-lane helpers ----------------
template<int CTRL>
__device__ __forceinline__ float dpp_add(float s) {
  int t = __builtin_amdgcn_update_dpp(0, __float_as_int(s), CTRL, 0xF, 0xF, true);
  return s + __int_as_float(t);
}
__device__ __forceinline__ float swz_add4(float s) {
  int t = __builtin_amdgcn_ds_swizzle(__float_as_int(s), 0x101F);  // xor 4
  return s + __int_as_float(t);
}

// monotone float<->uint ordering (for atomic max)
__device__ __forceinline__ unsigned ordf(float f) {
  unsigned b = __float_as_uint(f);
  return b ^ (((int)b >> 31) | 0x80000000u);
}
__device__ __forceinline__ float deordf(unsigned u) {
  unsigned b = (u & 0x80000000u) ? (u ^ 0x80000000u) : ~u;
  return __uint_as_float(b);
}

// ---------------- projection helpers ----------------
__device__ __forceinline__ void fuse_proj(const float* pm, float* P) {
  const float* E = pm;
  const float* K = pm + 16;
  for (int r = 0; r < 3; ++r)
    for (int c = 0; c < 4; ++c)
      P[r*4+c] = K[r*4+0]*E[0*4+c] + K[r*4+1]*E[1*4+c] + K[r*4+2]*E[2*4+c];
  for (int c = 0; c < 4; ++c) P[12+c] = E[12+c];
}

__device__ void invert4(const float* m, float* invOut) {
  float inv[16];
  inv[0]  =  m[5]*m[10]*m[15] - m[5]*m[11]*m[14] - m[9]*m[6]*m[15] + m[9]*m[7]*m[14] + m[13]*m[6]*m[11] - m[13]*m[7]*m[10];
  inv[4]  = -m[4]*m[10]*m[15] + m[4]*m[11]*m[14] + m[8]*m[6]*m[15] - m[8]*m[7]*m[14] - m[12]*m[6]*m[11] + m[12]*m[7]*m[10];
  inv[8]  =  m[4]*m[9]*m[15]  - m[4]*m[11]*m[13] - m[8]*m[5]*m[15] + m[8]*m[7]*m[13] + m[12]*m[5]*m[11] - m[12]*m[7]*m[9];
  inv[12] = -m[4]*m[9]*m[14]  + m[4]*m[10]*m[13] + m[8]*m[5]*m[14] - m[8]*m[6]*m[13] - m[12]*m[5]*m[10] + m[12]*m[6]*m[9];
  inv[1]  = -m[1]*m[10]*m[15] + m[1]*m[11]*m[14] + m[9]*m[2]*m[15] - m[9]*m[3]*m[14] - m[13]*m[2]*m[11] + m[13]*m[3]*m[10];
  inv[5]  =  m[0]*m[10]*m[15] - m[0]*m[11]*m[14] - m[8]*m[2]*m[15] + m[8]*m[3]*m[14] + m[12]*m[2]*m[11] - m[12]*m[3]*m[10];
  inv[9]  = -m[0]*m[9]*m[15]  + m[0]*m[11]*m[13] + m[8]*m[1]*m[15] - m[8]*m[3]*m[13] - m[12]*m[1]*m[11] + m[12]*m[3]*m[9];
  inv[13] =  m[0]*m[9]*m[14]  - m[0]*m[10]*m[13] - m[8]*m[1]*m[14] + m[8]*m[2]*m[13] + m[12]*m[1]*m[10] - m[12]*m[2]*m[9];
  inv[2]  =  m[1]*m[6]*m[15]  - m[1]*m[7]*m[14]  - m[5]*m[2]*m[15] + m[5]*m[3]*m[14] + m[13]*m[2]*m[7]  - m[13]*m[3]*m[6];
  inv[6]  = -m[0]*m[6]*m[15]  + m[0]*m[7]*m[14]  + m[4]*m[2]*m[15] - m[4]*m[3]*m[14] - m[12]*m[2]*m[7]  + m[12]*m[3]*m[6];
  inv[10] =  m[0]*m[5]*m[15]  - m[0]*m[7]*m[13]  - m[4]*m[1]*m[15] + m[4]*m[3]*m[13] + m[12]*m[1]*m[7]  - m[12]*m[3]*m[5];
  inv[14] = -m[0]*m[5]*m[14]  + m[0]*m[6]*m[13]  + m[4]*m[1]*m[14] - m[4]*m[2]*m[13] - m[12]*m[1]*m[6]  + m[12]*m[2]*m[5];
  inv[3]  = -m[1]*m[6]*m[11]  + m[1]*m[7]*m[10]  + m[5]*m[2]*m[11] - m[5]*m[3]*m[10] - m[9]*m[2]*m[7]   + m[9]*m[3]*m[6];
  inv[7]  =  m[0]*m[6]*m[11]  - m[0]*m[7]*m[10]  - m[4]*m[2]*m[11] + m[4]*m[3]*m[10] + m[8]*m[2]*m[7]   - m[8]*m[3]*m[6];
  inv[11] = -m[0]*m[5]*m[11]  + m[0]*m[7]*m[9]   + m[4]*m[1]*m[11] - m[4]*m[3]*m[9]  - m[8]*m[1]*m[7]   + m[8]*m[3]*m[5];
  inv[15] =  m[0]*m[5]*m[10]  - m[0]*m[6]*m[9]   - m[4]*m[1]*m[10] + m[4]*m[2]*m[9]  + m[8]*m[1]*m[6]   - m[8]*m[2]*m[5];
  float det = m[0]*inv[0] + m[1]*inv[4] + m[2]*inv[8] + m[3]*inv[12];
  det = 1.0f / det;
  for (int i = 0; i < 16; i++) invOut[i] = inv[i] * det;
}

// ---------------- prep: transpose + xform + zero pads/accumulators ---------
// grid (HW/64, 5). Transpose (V,C,H,W)->(V,HW,C) LDS-tiled (both sides
// coalesced). Block(0,0) additionally computes xf and zeroes the tf pad;
// blocks with y==0 zero vwu (one uint per thread).
__global__ void __launch_bounds__(256)
k_prep(const float* __restrict__ feat, const float* __restrict__ pm,
       float* __restrict__ tf, float* __restrict__ xf,
       unsigned* __restrict__ vwu) {
  __shared__ float tile[C_][64+1];
  int v  = blockIdx.y;
  int p0 = blockIdx.x * 64;
  int t  = threadIdx.x;

  if (v == 0) vwu[blockIdx.x*256 + t] = 0u;

  int pl = t & 63;
  int cg = t >> 6;            // 0..3
  const float* src = feat + (size_t)v*C_*HW + p0 + pl;
  #pragma unroll
  for (int k = 0; k < 8; ++k) {
    int c = cg*8 + k;
    tile[c][pl] = src[(size_t)c*HW];
  }
  __syncthreads();

  int pp = t >> 2;            // pixel 0..63
  int co = (t & 3) * 8;       // channel offset
  float4 a, b;
  a.x = tile[co+0][pp]; a.y = tile[co+1][pp]; a.z = tile[co+2][pp]; a.w = tile[co+3][pp];
  b.x = tile[co+4][pp]; b.y = tile[co+5][pp]; b.z = tile[co+6][pp]; b.w = tile[co+7][pp];
  float* dst = tf + ((size_t)v*HW + p0 + pp)*C_ + co;
  *(float4*)dst = a;
  *(float4*)(dst+4) = b;

  if (blockIdx.x == 0 && v == 0) {
    if (t < 64) tf[(size_t)5*HW*C_ + t] = 0.0f;   // zero pad (invalid corners)
    if (t == 0) {
      float Pr[16], Pinv[16], Ps[16], M[16];
      fuse_proj(pm, Pr);
      invert4(Pr, Pinv);
      for (int vv = 1; vv <= NV; ++vv) {
        fuse_proj(pm + vv*32, Ps);
        for (int r = 0; r < 4; ++r)
          for (int c = 0; c < 4; ++c) {
            float acc = 0.f;
            for (int k = 0; k < 4; ++k) acc += Ps[r*4+k]*Pinv[k*4+c];
            M[r*4+c] = acc;
          }
        float* o = xf + (vv-1)*12;
        o[0]=M[0];  o[1]=M[1];  o[2]=M[2];
        o[3]=M[4];  o[4]=M[5];  o[5]=M[6];
        o[6]=M[8];  o[7]=M[9];  o[8]=M[10];
        o[9]=M[3];  o[10]=M[7]; o[11]=M[11];
      }
    }
  }
}

// ---------------- main warp + similarity kernel ----------------
// Wave = 8 pixels x 8 slots. Per 8-depth block:
//   phase 1: each lane builds the descriptor for ONE (pixel,depth) item:
//            4 corner byte-offsets + 4 bilinear weights (shared exact 1/Z).
//   phase 2: per depth, 2 b128 LDS reads recover the descriptor. Corner
//            transitions along the epipolar line are single-texel x-shifts,
//            so three wave-uniform paths: full-skip (corners unchanged),
//            shift (reuse 2 dots, load 2 corners), full reload (4 corners).
__global__ void __launch_bounds__(256)
k_warp(const float* __restrict__ tf, const float* __restrict__ dv,
       const float* __restrict__ xf, float* __restrict__ sim_all) {
  __shared__ int4   dso[4][64];
  __shared__ float4 dsw[4][64];

  int lane = threadIdx.x & 63;
  int wv = threadIdx.x >> 6;
  int ch = lane & 7;              // channel chunk (phase 2) / depth slot (phase 1)
  int pix = (lane >> 3) & 7;      // pixel within group
  int wvg = __builtin_amdgcn_readfirstlane((blockIdx.x*256 + threadIdx.x) >> 6);
  const int PGPV = HW/8;
  int pg = wvg % PGPV;
  int v  = wvg / PGPV;
  int p  = pg*8 + pix;

  float xpix = (float)(p % W_);
  float ypix = (float)(p / W_);

  const float* M = xf + v*12;
  float rx = M[0]*xpix + M[1]*ypix + M[2];
  float ry = M[3]*xpix + M[4]*ypix + M[5];
  float rz = M[6]*xpix + M[7]*ypix + M[8];
  float t0 = M[9], t1 = M[10], t2 = M[11];

  // ref fragment, pre-scaled by 1/C (folds the sim normalization)
  float4 rfc = *(const float4*)(tf + (size_t)p*C_ + ch*4);
  rfc.x *= (1.0f/(float)C_); rfc.y *= (1.0f/(float)C_);
  rfc.z *= (1.0f/(float)C_); rfc.w *= (1.0f/(float)C_);

  const char* tfb = (const char*)(tf + (size_t)(v+1)*HW*C_);
  const int chb = ch*16;
  const int ZB = (4-v)*HW*C_*4;   // byte offset (from view base) of zero pad

  float* simv = sim_all + (size_t)v*D_*HW + p;

  int4 P = make_int4(-1,-1,-1,-1);
  float d00 = 0.f, d01 = 0.f, d10 = 0.f, d11 = 0.f;

  for (int b = 0; b < D_/DB; ++b) {
    // ---- phase 1: one descriptor per lane, staged to LDS ----
    int d1 = b*DB + ch;
    float dep = dv[(size_t)d1*HW + p];
    float Z  = rz*dep + t2;
    float zr = 1.0f / Z;                // exact reciprocal, shared by px,py
    float px = (rx*dep + t0) * zr;
    float py = (ry*dep + t1) * zr;
    float x0f = floorf(px), y0f = floorf(py);
    float wx1 = px - x0f;
    float wy1 = py - y0f;
    float wx0 = 1.0f - wx1, wy0 = 1.0f - wy1;
    int x0 = (int)x0f, y0 = (int)y0f;
    int x1 = x0 + 1,   y1 = y0 + 1;
    bool vx0 = ((unsigned)x0 <= (unsigned)(W_-1));
    bool vx1 = ((unsigned)x1 <= (unsigned)(W_-1));
    bool vy0 = ((unsigned)y0 <= (unsigned)(H_-1));
    bool vy1 = ((unsigned)y1 <= (unsigned)(H_-1));
    int cx0 = min(max(x0, 0), W_-1);
    int cx1 = min(max(x1, 0), W_-1);
    int cy0 = min(max(y0, 0), H_-1);
    int cy1 = min(max(y1, 0), H_-1);
    int r0 = cy0*W_, r1 = cy1*W_;
    int o00 = (vx0 && vy0) ? (r0+cx0)*(C_*4) : ZB;
    int o01 = (vx1 && vy0) ? (r0+cx1)*(C_*4) : ZB;
    int o10 = (vx0 && vy1) ? (r1+cx0)*(C_*4) : ZB;
    int o11 = (vx1 && vy1) ? (r1+cx1)*(C_*4) : ZB;

    int key = (ch<<3) | (pix ^ ch);          // bank-uniform for write & read
    dso[wv][key] = make_int4(o00, o01, o10, o11);
    dsw[wv][key] = make_float4(wx0*wy0, wx1*wy0, wx0*wy1, wx1*wy1);

    // ---- phase 2: 8 depths; descriptor via 2 b128 LDS reads ----
    #pragma unroll
    for (int dd = 0; dd < DB; ++dd) {
      int it = (dd<<3) | (pix ^ dd);
      int4   O  = dso[wv][it];
      float4 Wt = dsw[wv][it];

      bool m = (O.x != P.x) || (O.y != P.y) || (O.z != P.z) || (O.w != P.w);
      if (__any(m)) {
        bool sp = (O.x == P.y) && (O.z == P.w);   // +x texel shift
        bool sm = (O.y == P.x) && (O.w == P.z);   // -x texel shift
        if (__all(!m || sp)) {
          d00 = m ? d01 : d00;
          d10 = m ? d11 : d10;
          float4 bq = *(const float4*)(tfb + (O.y + chb));
          float4 e  = *(const float4*)(tfb + (O.w + chb));
          d01 = bq.x*rfc.x + bq.y*rfc.y + bq.z*rfc.z + bq.w*rfc.w;
          d11 = e.x*rfc.x  + e.y*rfc.y  + e.z*rfc.z  + e.w*rfc.w;
        } else if (__all(!m || sm)) {
          d01 = m ? d00 : d01;
          d11 = m ? d10 : d11;
          float4 a = *(const float4*)(tfb + (O.x + chb));
          float4 g = *(const float4*)(tfb + (O.z + chb));
          d00 = a.x*rfc.x + a.y*rfc.y + a.z*rfc.z + a.w*rfc.w;
          d10 = g.x*rfc.x + g.y*rfc.y + g.z*rfc.z + g.w*rfc.w;
        } else {
          float4 a  = *(const float4*)(tfb + (O.x + chb));
          float4 bq = *(const float4*)(tfb + (O.y + chb));
          float4 g  = *(const float4*)(tfb + (O.z + chb));
          float4 e  = *(const float4*)(tfb + (O.w + chb));
          d00 = a.x*rfc.x  + a.y*rfc.y  + a.z*rfc.z  + a.w*rfc.w;
          d01 = bq.x*rfc.x + bq.y*rfc.y + bq.z*rfc.z + bq.w*rfc.w;
          d10 = g.x*rfc.x  + g.y*rfc.y  + g.z*rfc.z  + g.w*rfc.w;
          d11 = e.x*rfc.x  + e.y*rfc.y  + e.z*rfc.z  + e.w*rfc.w;
        }
      }
      P = O;

      float s = Wt.x*d00 + Wt.y*d01 + Wt.z*d10 + Wt.w*d11;
      s = dpp_add<0xB1>(s);   // xor 1
      s = dpp_add<0x4E>(s);   // xor 2
      s = swz_add4(s);        // xor 4
      if (ch == 0) simv[(size_t)(b*DB + dd)*HW] = s;
    }
  }
}

// ---------------- MLP: 4 depths per thread, atomic-max logit -------------
__global__ void __launch_bounds__(256)
k_mlp(const float* __restrict__ sim_all,
      const float* __restrict__ w0, const float* __restrict__ b0,
      const float* __restrict__ w1, const float* __restrict__ b1,
      const float* __restrict__ w2, const float* __restrict__ b2,
      unsigned* __restrict__ vwu) {
  int idx = blockIdx.x*blockDim.x + threadIdx.x;
  if (idx >= NV*(D_/4)*HW) return;
  int p = idx % HW;
  int t = idx / HW;           // (v, chunk)
  int v = t / (D_/4);
  int c = t % (D_/4);

  const float* sp_ = sim_all + ((size_t)(v*D_ + c*4))*HW + p;
  float sv[4];
  sv[0] = sp_[0];
  sv[1] = sp_[HW];
  sv[2] = sp_[2*HW];
  sv[3] = sp_[3*HW];

  float ymax = -3.0e38f;
  #pragma unroll
  for (int k = 0; k < 4; ++k) {
    float s = sv[k];
    float acc0 = b1[0], acc1 = b1[1], acc2 = b1[2], acc3 = b1[3];
    float acc4 = b1[4], acc5 = b1[5], acc6 = b1[6], acc7 = b1[7];
    #pragma unroll
    for (int o = 0; o < 16; ++o) {
      float h = fmaxf(fmaf(w0[o], s, b0[o]), 0.0f);
      acc0 = fmaf(w1[0*16+o], h, acc0);
      acc1 = fmaf(w1[1*16+o], h, acc1);
      acc2 = fmaf(w1[2*16+o], h, acc2);
      acc3 = fmaf(w1[3*16+o], h, acc3);
      acc4 = fmaf(w1[4*16+o], h, acc4);
      acc5 = fmaf(w1[5*16+o], h, acc5);
      acc6 = fmaf(w1[6*16+o], h, acc6);
      acc7 = fmaf(w1[7*16+o], h, acc7);
    }
    float yv = b2[0];
    yv = fmaf(w2[0], fmaxf(acc0, 0.0f), yv);
    yv = fmaf(w2[1], fmaxf(acc1, 0.0f), yv);
    yv = fmaf(w2[2], fmaxf(acc2, 0.0f), yv);
    yv = fmaf(w2[3], fmaxf(acc3, 0.0f), yv);
    yv = fmaf(w2[4], fmaxf(acc4, 0.0f), yv);
    yv = fmaf(w2[5], fmaxf(acc5, 0.0f), yv);
    yv = fmaf(w2[6], fmaxf(acc6, 0.0f), yv);
    yv = fmaf(w2[7], fmaxf(acc7, 0.0f), yv);
    ymax = fmaxf(ymax, yv);
  }
  atomicMax(&vwu[(size_t)v*HW + p], ordf(ymax));
}

// ---------------- fused: vw-decode + fuse + conv + softmax/argmax ----------
__global__ void __launch_bounds__(256)
k_fct(const float* __restrict__ sim_all, const unsigned* __restrict__ vwu,
      const float* __restrict__ rw, const float* __restrict__ rb,
      const float* __restrict__ dv, float* __restrict__ out) {
  __shared__ float sfus[D_][TYH][TXH+1];
  __shared__ float scost[D_][64];
  __shared__ float svw[NV][NCOL];
  __shared__ float sinvw[NCOL];
  __shared__ int   sgpc[NCOL];

  int tid = threadIdx.x;
  int gx0 = blockIdx.x*TX;
  int gy0 = blockIdx.y*TY;

  // phase A: per-column view weights (decode + sigmoid) / inv wsum / pixel idx
  if (tid < NCOL) {
    int yy = tid / TXH, xx = tid % TXH;
    int gy = gy0 + yy - 1, gx = gx0 + xx - 1;
    bool valid = (gx >= 0) && (gx < W_) && (gy >= 0) && (gy < H_);
    int gp = min(max(gy,0),H_-1)*W_ + min(max(gx,0),W_-1);
    sgpc[tid] = gp;
    float a0 = 1.0f/(1.0f + expf(-deordf(vwu[0*HW+gp])));
    float a1 = 1.0f/(1.0f + expf(-deordf(vwu[1*HW+gp])));
    float a2 = 1.0f/(1.0f + expf(-deordf(vwu[2*HW+gp])));
    float a3 = 1.0f/(1.0f + expf(-deordf(vwu[3*HW+gp])));
    float inv = valid ? 1.0f/(1e-5f + a0+a1+a2+a3) : 0.0f;
    if (!valid) { a0=a1=a2=a3=0.f; }
    svw[0][tid]=a0; svw[1][tid]=a1; svw[2][tid]=a2; svw[3][tid]=a3;
    sinvw[tid] = inv;
  }
  __syncthreads();

  // phase B: fill fused volume tile (invalid columns auto-zero via weights)
  for (int j = tid; j < D_*NCOL; j += 256) {
    int d = j / NCOL, r = j % NCOL;
    int gp = sgpc[r];
    float s0 = sim_all[(size_t)(0*D_+d)*HW + gp];
    float s1 = sim_all[(size_t)(1*D_+d)*HW + gp];
    float s2 = sim_all[(size_t)(2*D_+d)*HW + gp];
    float s3 = sim_all[(size_t)(3*D_+d)*HW + gp];
    float val = (s0*svw[0][r] + s1*svw[1][r] + s2*svw[2][r] + s3*svw[3][r]) * sinvw[r];
    int yy = r / TXH, xx = r % TXH;
    sfus[d][yy][xx] = val;
  }
  __syncthreads();

  // phase C: 3x3x3 conv; thread = (pixel, depth-group of 12)
  {
    int pid = tid & 63;
    int dg  = tid >> 6;
    int px = pid & 15, py = pid >> 4;
    float kw[27];
    #pragma unroll
    for (int i = 0; i < 27; ++i) kw[i] = rw[i];
    float bias = rb[0];

    float pm1[9], p0[9], pp1[9];
    int d0 = dg*12;
    #pragma unroll
    for (int i = 0; i < 9; ++i) {
      int ky = i/3, kx = i%3;
      pm1[i] = (d0 > 0) ? sfus[d0-1][py+ky][px+kx] : 0.0f;
      p0[i]  = sfus[d0][py+ky][px+kx];
    }
    #pragma unroll
    for (int k = 0; k < 12; ++k) {
      int d = d0 + k;
      #pragma unroll
      for (int i = 0; i < 9; ++i) {
        int ky = i/3, kx = i%3;
        pp1[i] = (d+1 < D_) ? sfus[d+1][py+ky][px+kx] : 0.0f;
      }
      float acc = bias;
      #pragma unroll
      for (int i = 0; i < 9; ++i) acc += pm1[i]*kw[i];
      #pragma unroll
      for (int i = 0; i < 9; ++i) acc += p0[i]*kw[9+i];
      #pragma unroll
      for (int i = 0; i < 9; ++i) acc += pp1[i]*kw[18+i];
      scost[d][pid] = acc;
      #pragma unroll
      for (int i = 0; i < 9; ++i) { pm1[i] = p0[i]; p0[i] = pp1[i]; }
    }
  }
  __syncthreads();

  // phase D: softmax / argmax / outputs, one thread per pixel
  if (tid < 64) {
    int tx = tid & 15, ty = tid >> 4;
    int gx = gx0 + tx, gy = gy0 + ty;
    int gp = gy*W_ + gx;
    float vmax = scost[0][tid];
    int am = 0;
    #pragma unroll
    for (int d = 1; d < D_; ++d) {
      float c = scost[d][tid];
      if (c > vmax) { vmax = c; am = d; }
    }
    float sum = 0.0f;
    #pragma unroll
    for (int d = 0; d < D_; ++d) sum += expf(scost[d][tid] - vmax);
    float inv = 1.0f / sum;
    #pragma unroll
    for (int d = 0; d < D_; ++d)
      out[(size_t)(2*HW) + (size_t)d*HW + gp] = expf(scost[d][tid] - vmax) * inv;
    out[gp] = dv[(size_t)am*HW + gp];
    out[HW + gp] = inv;
    // view_weights output
    int rint = (ty+1)*TXH + (tx+1);
    #pragma unroll
    for (int v = 0; v < NV; ++v)
      out[(size_t)(2*HW + D_*HW) + (size_t)v*HW + gp] = svw[v][rint];
  }
}

// ---------------- launch ----------------
extern "C" void kernel_launch(void* const* d_in, const int* in_sizes, int n_in,
                              void* d_out, int out_size, void* d_ws, size_t ws_size,
                              hipStream_t stream) {
  const float* feat = (const float*)d_in[0];
  const float* pm   = (const float*)d_in[1];
  const float* dv   = (const float*)d_in[2];
  const float* w0   = (const float*)d_in[3];
  const float* b0   = (const float*)d_in[4];
  const float* w1   = (const float*)d_in[5];
  const float* b1   = (const float*)d_in[6];
  const float* w2   = (const float*)d_in[7];
  const float* b2   = (const float*)d_in[8];
  const float* rw   = (const float*)d_in[9];
  const float* rb   = (const float*)d_in[10];
  float* out = (float*)d_out;
  float* ws  = (float*)d_ws;

  // workspace layout (floats)
  float*    xf  = ws;                        // 48 (pad 64)
  float*    tf  = ws + 64;                   // 5*HW*C + 64 zero-pad
  float*    sim = ws + 3276928;              // 4*48*HW = 3,932,160
  unsigned* vwu = (unsigned*)(ws + 7209088); // 4*HW = 81,920
  // high-water mark: ~7.29M floats = ~27.9 MB

  hipLaunchKernelGGL(k_prep, dim3(HW/64, 5), dim3(256), 0, stream,
                     feat, pm, tf, xf, vwu);
  hipLaunchKernelGGL(k_warp, dim3((NV*HW*8)/256), dim3(256), 0, stream,
                     tf, dv, xf, sim);
  hipLaunchKernelGGL(k_mlp, dim3((NV*(D_/4)*HW)/256), dim3(256), 0, stream,
                     sim, w0, b0, w1, b1, w2, b2, vwu);
  hipLaunchKernelGGL(k_fct, dim3(W_/TX, H_/TY), dim3(256), 0, stream,
                     sim, vwu, rw, rb, dv, out);
}